// Round 7
// baseline (339.776 us; speedup 1.0000x reference)
//
#include <hip/hip_runtime.h>
#include <hip/hip_bf16.h>

#define B_ 32
#define K_ 4
#define N_ 512
#define F_ 128

typedef __attribute__((ext_vector_type(8))) short short8;
typedef __attribute__((ext_vector_type(4))) short short4v;
typedef __attribute__((ext_vector_type(4))) float float4v;

__device__ __forceinline__ unsigned short f2bf(float x) {
    unsigned int u = __builtin_bit_cast(unsigned int, x);
    u += 0x7FFFu + ((u >> 16) & 1u);
    return (unsigned short)(u >> 16);
}

__device__ __forceinline__ short8 pack8(float4v a, float4v b) {
    short8 r;
    r[0] = (short)f2bf(a[0]); r[1] = (short)f2bf(a[1]);
    r[2] = (short)f2bf(a[2]); r[3] = (short)f2bf(a[3]);
    r[4] = (short)f2bf(b[0]); r[5] = (short)f2bf(b[1]);
    r[6] = (short)f2bf(b[2]); r[7] = (short)f2bf(b[3]);
    return r;
}

// ---------------- k0: weight transposes (tiny) ----------------
__global__ void k0_weights(const float* __restrict__ RW, const float* __restrict__ SW,
                           unsigned short* __restrict__ Wt, unsigned short* __restrict__ SWt) {
    int r = blockIdx.x;   // 0..639
    int m = threadIdx.x;  // 0..127
    if (r < 512) {
        int k = r >> 7, f = r & 127;
        Wt[r * F_ + m] = f2bf(RW[(m * F_ + f) * K_ + k]);
    } else {
        int l = r - 512;
        SWt[l * F_ + m] = f2bf(SW[m * F_ + l]);
    }
}

// ---------------- k1v2: colsum + E->bf16 conversion (E read ONCE) ----------------
// grid: b(32) x isl(16) x jt(2) = 1024 blocks, 256 threads.
// thread t: j = jt*256 + (t&63)*4 (4 consecutive cols), rows = isl*32 + (t>>6)*8 .. +8
__global__ void k1v2_convert(const float* __restrict__ E, float* __restrict__ colsum,
                             unsigned short* __restrict__ Ebf) {
    int bid = blockIdx.x;
    int b   = bid >> 5;
    int isl = (bid >> 1) & 15;
    int jt  = bid & 1;
    int t   = threadIdx.x;
    int j   = jt * 256 + (t & 63) * 4;
    int r0  = isl * 32 + (t >> 6) * 8;

    float cs0 = 0.f, cs1 = 0.f, cs2 = 0.f, cs3 = 0.f;
#pragma unroll
    for (int k = 0; k < K_; ++k) {
        const float* Ep = E + ((size_t)((b * K_ + k) * N_ + r0)) * N_ + j;
        unsigned short* Op = Ebf + ((size_t)((b * K_ + k) * N_ + r0)) * N_ + j;
#pragma unroll
        for (int r = 0; r < 8; ++r) {
            float4v v = *(const float4v*)(Ep + (size_t)r * N_);
            cs0 += v[0]; cs1 += v[1]; cs2 += v[2]; cs3 += v[3];
            short4v s;
            s[0] = (short)f2bf(v[0]); s[1] = (short)f2bf(v[1]);
            s[2] = (short)f2bf(v[2]); s[3] = (short)f2bf(v[3]);
            *(short4v*)(Op + (size_t)r * N_) = s;
        }
    }
    atomicAdd(&colsum[b * N_ + j + 0], cs0);
    atomicAdd(&colsum[b * N_ + j + 1], cs1);
    atomicAdd(&colsum[b * N_ + j + 2], cs2);
    atomicAdd(&colsum[b * N_ + j + 3], cs3);
}

// ---------------- k2: Tt[b][c][j] = sum_m Wt[c][m] * H[b][j][m]  (validated r0 version) ----
__global__ void k2_expand(const float* __restrict__ H, const unsigned short* __restrict__ Wt,
                          unsigned short* __restrict__ Tt) {
    int bid = blockIdx.x;        // 1024 blocks
    int b  = bid >> 5;
    int ct = (bid >> 2) & 7;
    int jt = bid & 3;
    int lane = threadIdx.x & 63;
    int wv   = threadIdx.x >> 6;
    int c0 = ct * 64 + wv * 16;
    int jbase = jt * 128;
    int lrow = lane & 15, lgrp = lane >> 4;

    float4v acc[8];
#pragma unroll
    for (int i = 0; i < 8; ++i) acc[i] = {0.f, 0.f, 0.f, 0.f};

#pragma unroll
    for (int ms = 0; ms < 4; ++ms) {
        int m0 = ms * 32;
        short8 a = *(const short8*)(Wt + (c0 + lrow) * F_ + m0 + lgrp * 8);
#pragma unroll
        for (int cf = 0; cf < 8; ++cf) {
            int j = jbase + cf * 16 + lrow;
            const float* hp = H + ((size_t)b * N_ + j) * F_ + m0 + lgrp * 8;
            float4v h0 = *(const float4v*)hp;
            float4v h1 = *(const float4v*)(hp + 4);
            short8 bb = pack8(h0, h1);
            acc[cf] = __builtin_amdgcn_mfma_f32_16x16x32_bf16(a, bb, acc[cf], 0, 0, 0);
        }
    }
#pragma unroll
    for (int cf = 0; cf < 8; ++cf) {
#pragma unroll
        for (int r = 0; r < 4; ++r) {
            int c = c0 + lgrp * 4 + r;
            int j = jbase + cf * 16 + lrow;
            Tt[((size_t)b * 512 + c) * N_ + j] = f2bf(acc[cf][r]);
        }
    }
}

// ---------------- k3v2: rel partials, software-pipelined ----------------
// grid: b(32) x it(8) x jc(2) = 512 blocks, 512 threads (8 waves: 4 i-sub x 2 f-half).
// K-loop: 32 iters (k 0..3 x js 0..7), j-chunk = jc*256 .. +256.
__global__ void __launch_bounds__(512)
k3v2_rel(const unsigned short* __restrict__ Ebf, const unsigned short* __restrict__ Tt,
         float* __restrict__ relP) {
    int bid = blockIdx.x;
    int b  = bid >> 4;
    int it = (bid >> 1) & 7;
    int jc = bid & 1;
    int lane = threadIdx.x & 63;
    int wv   = threadIdx.x >> 6;
    int i0 = it * 64 + (wv >> 1) * 16;
    int f0 = (wv & 1) * 64;
    int lrow = lane & 15, lgrp = lane >> 4;
    int jbase = jc * 256;

    float4v acc[4];
#pragma unroll
    for (int i = 0; i < 4; ++i) acc[i] = {0.f, 0.f, 0.f, 0.f};

    // iter t: k = t>>3, js = t&7. E stride/k = 262144, /js = 32. T stride/k = 65536, /cf = 8192, /js = 32.
    const unsigned short* Eb = Ebf + ((size_t)(b * K_) * N_ + (i0 + lrow)) * N_ + jbase + lgrp * 8;
    const unsigned short* Tb = Tt + ((size_t)b * 512 + f0 + lrow) * N_ + jbase + lgrp * 8;

#define EA(t) (const short8*)(Eb + ((t) >> 3) * 262144 + ((t) & 7) * 32)
#define TA(t, cf) (const short8*)(Tb + ((t) >> 3) * 65536 + (cf) * 8192 + ((t) & 7) * 32)

    short8 a0, b00, b01, b02, b03;
    short8 a1, b10, b11, b12, b13;
    a0 = *EA(0); b00 = *TA(0, 0); b01 = *TA(0, 1); b02 = *TA(0, 2); b03 = *TA(0, 3);

    for (int t = 0; t < 32; t += 2) {
        int t1 = t + 1;
        int t2 = (t + 2 < 32) ? t + 2 : 31;  // tail: harmless duplicate load
        // issue next-iter loads, then consume current (loads overlap MFMA)
        a1 = *EA(t1); b10 = *TA(t1, 0); b11 = *TA(t1, 1); b12 = *TA(t1, 2); b13 = *TA(t1, 3);
        acc[0] = __builtin_amdgcn_mfma_f32_16x16x32_bf16(a0, b00, acc[0], 0, 0, 0);
        acc[1] = __builtin_amdgcn_mfma_f32_16x16x32_bf16(a0, b01, acc[1], 0, 0, 0);
        acc[2] = __builtin_amdgcn_mfma_f32_16x16x32_bf16(a0, b02, acc[2], 0, 0, 0);
        acc[3] = __builtin_amdgcn_mfma_f32_16x16x32_bf16(a0, b03, acc[3], 0, 0, 0);
        a0 = *EA(t2); b00 = *TA(t2, 0); b01 = *TA(t2, 1); b02 = *TA(t2, 2); b03 = *TA(t2, 3);
        acc[0] = __builtin_amdgcn_mfma_f32_16x16x32_bf16(a1, b10, acc[0], 0, 0, 0);
        acc[1] = __builtin_amdgcn_mfma_f32_16x16x32_bf16(a1, b11, acc[1], 0, 0, 0);
        acc[2] = __builtin_amdgcn_mfma_f32_16x16x32_bf16(a1, b12, acc[2], 0, 0, 0);
        acc[3] = __builtin_amdgcn_mfma_f32_16x16x32_bf16(a1, b13, acc[3], 0, 0, 0);
    }
#undef EA
#undef TA

    float* dst = relP + (size_t)jc * (B_ * N_ * F_);
#pragma unroll
    for (int cf = 0; cf < 4; ++cf) {
#pragma unroll
        for (int r = 0; r < 4; ++r) {
            int i = i0 + lgrp * 4 + r;
            int f = f0 + cf * 16 + lrow;
            dst[((size_t)b * N_ + i) * F_ + f] = acc[cf][r];
        }
    }
}

// ---------------- k4: epilogue — self-term MFMA + D*(relA+relB) + sigmoid ----------------
// grid: b(32) x it(8) = 256 blocks, 512 threads.
__global__ void __launch_bounds__(512)
k4_epi(const float* __restrict__ relP, const float* __restrict__ H,
       const unsigned short* __restrict__ SWt, const float* __restrict__ colsum,
       float* __restrict__ out) {
    int bid = blockIdx.x;
    int b  = bid >> 3;
    int it = bid & 7;
    int lane = threadIdx.x & 63;
    int wv   = threadIdx.x >> 6;
    int i0 = it * 64 + (wv >> 1) * 16;
    int f0 = (wv & 1) * 64;
    int lrow = lane & 15, lgrp = lane >> 4;

    float4v accS[4];
#pragma unroll
    for (int i = 0; i < 4; ++i) accS[i] = {0.f, 0.f, 0.f, 0.f};

    const float* Hp = H + ((size_t)b * N_ + i0 + lrow) * F_;
#pragma unroll
    for (int ms = 0; ms < 4; ++ms) {
        int m0 = ms * 32;
        const float* hp = Hp + m0 + lgrp * 8;
        float4v h0 = *(const float4v*)hp;
        float4v h1 = *(const float4v*)(hp + 4);
        short8 a = pack8(h0, h1);
#pragma unroll
        for (int cf = 0; cf < 4; ++cf) {
            const unsigned short* sp = SWt + (f0 + cf * 16 + lrow) * F_ + m0 + lgrp * 8;
            short8 bb = *(const short8*)sp;
            accS[cf] = __builtin_amdgcn_mfma_f32_16x16x32_bf16(a, bb, accS[cf], 0, 0, 0);
        }
    }

    float Dv[4];
#pragma unroll
    for (int r = 0; r < 4; ++r) {
        int i = i0 + lgrp * 4 + r;
        Dv[r] = 1.0f / (colsum[b * N_ + i] + (float)K_);
    }
#pragma unroll
    for (int cf = 0; cf < 4; ++cf) {
#pragma unroll
        for (int r = 0; r < 4; ++r) {
            int i = i0 + lgrp * 4 + r;
            int f = f0 + cf * 16 + lrow;
            size_t idx = ((size_t)b * N_ + i) * F_ + f;
            float v = relP[idx] + relP[idx + (size_t)B_ * N_ * F_];
            float x = Dv[r] * v + accS[cf][r];
            out[idx] = 1.0f / (1.0f + __expf(-x));
        }
    }
}

// ================= fallback (validated round-0 kernels) =================
__global__ void k1_colsum(const float* __restrict__ E, float* __restrict__ colsum) {
    int bid = blockIdx.x;
    int b   = bid >> 5;
    int jt  = (bid >> 4) & 1;
    int isl = bid & 15;
    int j   = jt * 256 + threadIdx.x;
    int i0  = isl * 32;
    float s0 = 0.f, s1 = 0.f, s2 = 0.f, s3 = 0.f;
#pragma unroll
    for (int k = 0; k < K_; ++k) {
        const float* p = E + ((size_t)((b * K_ + k) * N_ + i0)) * N_ + j;
#pragma unroll 4
        for (int ii = 0; ii < 32; ii += 4) {
            s0 += p[(ii + 0) * N_];
            s1 += p[(ii + 1) * N_];
            s2 += p[(ii + 2) * N_];
            s3 += p[(ii + 3) * N_];
        }
    }
    atomicAdd(&colsum[b * N_ + j], (s0 + s1) + (s2 + s3));
}

__global__ void __launch_bounds__(512)
k3_fuse(const float* __restrict__ E, const float* __restrict__ H,
        const unsigned short* __restrict__ Tt, const unsigned short* __restrict__ SWt,
        const float* __restrict__ colsum, float* __restrict__ out) {
    int bid = blockIdx.x;
    int b  = bid >> 3;
    int it = bid & 7;
    int lane = threadIdx.x & 63;
    int wv   = threadIdx.x >> 6;
    int i0 = it * 64 + (wv >> 1) * 16;
    int f0 = (wv & 1) * 64;
    int lrow = lane & 15, lgrp = lane >> 4;

    float4v accR[4], accS[4];
#pragma unroll
    for (int i = 0; i < 4; ++i) { accR[i] = {0.f, 0.f, 0.f, 0.f}; accS[i] = {0.f, 0.f, 0.f, 0.f}; }

    for (int k = 0; k < K_; ++k) {
        const float* Eb = E + ((size_t)((b * K_ + k) * N_ + i0 + lrow)) * N_;
        const unsigned short* Tb = Tt + ((size_t)b * 512 + k * 128 + f0) * N_;
#pragma unroll 2
        for (int js = 0; js < 16; ++js) {
            int j0 = js * 32;
            const float* ep = Eb + j0 + lgrp * 8;
            float4v e0 = *(const float4v*)ep;
            float4v e1 = *(const float4v*)(ep + 4);
            short8 a = pack8(e0, e1);
#pragma unroll
            for (int cf = 0; cf < 4; ++cf) {
                const unsigned short* tp = Tb + (size_t)(cf * 16 + lrow) * N_ + j0 + lgrp * 8;
                short8 bb = *(const short8*)tp;
                accR[cf] = __builtin_amdgcn_mfma_f32_16x16x32_bf16(a, bb, accR[cf], 0, 0, 0);
            }
        }
    }
    {
        const float* Hp = H + ((size_t)b * N_ + i0 + lrow) * F_;
#pragma unroll
        for (int ms = 0; ms < 4; ++ms) {
            int m0 = ms * 32;
            const float* hp = Hp + m0 + lgrp * 8;
            float4v h0 = *(const float4v*)hp;
            float4v h1 = *(const float4v*)(hp + 4);
            short8 a = pack8(h0, h1);
#pragma unroll
            for (int cf = 0; cf < 4; ++cf) {
                const unsigned short* sp = SWt + (f0 + cf * 16 + lrow) * F_ + m0 + lgrp * 8;
                short8 bb = *(const short8*)sp;
                accS[cf] = __builtin_amdgcn_mfma_f32_16x16x32_bf16(a, bb, accS[cf], 0, 0, 0);
            }
        }
    }
    float Dv[4];
#pragma unroll
    for (int r = 0; r < 4; ++r) {
        int i = i0 + lgrp * 4 + r;
        Dv[r] = 1.0f / (colsum[b * N_ + i] + (float)K_);
    }
#pragma unroll
    for (int cf = 0; cf < 4; ++cf) {
#pragma unroll
        for (int r = 0; r < 4; ++r) {
            int i = i0 + lgrp * 4 + r;
            int f = f0 + cf * 16 + lrow;
            float x = Dv[r] * accR[cf][r] + accS[cf][r];
            out[((size_t)b * N_ + i) * F_ + f] = 1.0f / (1.0f + __expf(-x));
        }
    }
}

extern "C" void kernel_launch(void* const* d_in, const int* in_sizes, int n_in,
                              void* d_out, int out_size, void* d_ws, size_t ws_size,
                              hipStream_t stream) {
    const float* H  = (const float*)d_in[0];
    const float* E  = (const float*)d_in[1];
    const float* RW = (const float*)d_in[2];
    const float* SW = (const float*)d_in[3];
    float* out = (float*)d_out;

    char* ws = (char*)d_ws;
    unsigned short* Wt  = (unsigned short*)(ws);               // 128 KiB
    unsigned short* SWt = (unsigned short*)(ws + 131072);      //  32 KiB
    float* colsum       = (float*)(ws + 163840);               //  64 KiB
    unsigned short* Tt  = (unsigned short*)(ws + 262144);      //  16 MiB
    unsigned short* Ebf = (unsigned short*)(ws + 17039360);    //  64 MiB
    float* relP         = (float*)(ws + 84148224);             //  16 MiB (2 x 8 MiB)
    const size_t WS_NEED = 100925440ull;

    hipMemsetAsync(colsum, 0, B_ * N_ * sizeof(float), stream);
    k0_weights<<<640, 128, 0, stream>>>(RW, SW, Wt, SWt);

    if (ws_size >= WS_NEED) {
        k1v2_convert<<<1024, 256, 0, stream>>>(E, colsum, Ebf);
        k2_expand<<<1024, 256, 0, stream>>>(H, Wt, Tt);
        k3v2_rel<<<512, 512, 0, stream>>>(Ebf, Tt, relP);
        k4_epi<<<256, 512, 0, stream>>>(relP, H, SWt, colsum, out);
    } else {
        k1_colsum<<<1024, 256, 0, stream>>>(E, colsum);
        k2_expand<<<1024, 256, 0, stream>>>(H, Wt, Tt);
        k3_fuse<<<256, 512, 0, stream>>>(E, H, Tt, SWt, colsum, out);
    }
}